// Round 6
// baseline (527.564 us; speedup 1.0000x reference)
//
#include <hip/hip_runtime.h>
#include <hip/hip_bf16.h>

typedef unsigned int uint;
typedef unsigned short ushort;
typedef __attribute__((ext_vector_type(8))) short bf16x8;
typedef __attribute__((ext_vector_type(4))) float f32x4;

__device__ __forceinline__ float bf2f(ushort u) {
    return __uint_as_float(((uint)u) << 16);
}
__device__ __forceinline__ ushort f2bf(float f) {
    uint u = __float_as_uint(f);
    u += 0x7FFFu + ((u >> 16) & 1u);   // round-to-nearest-even
    return (ushort)(u >> 16);
}
__device__ __forceinline__ uint cvtpk(float lo, float hi) {
    uint r;
    asm("v_cvt_pk_bf16_f32 %0, %1, %2" : "=v"(r) : "v"(lo), "v"(hi));
    return r;
}
__device__ __forceinline__ float sigm(float x) {
    return 1.0f / (1.0f + expf(-x));
}
// async global->LDS DMA, 16 B per lane; lds dest = wave-uniform base + lane*16
__device__ __forceinline__ void dma16(const void* g, void* l) {
    __builtin_amdgcn_global_load_lds(
        (const __attribute__((address_space(1))) void*)g,
        (__attribute__((address_space(3))) void*)l, 16, 0, 0);
}

// ---------------- kernel 1: fused kP (blocks 0-95) + kW (blocks 96-119)
__global__ __launch_bounds__(512) void kPW(
    const float* __restrict__ emb, const float* __restrict__ w_ih,
    const float* __restrict__ b_ih, float* __restrict__ P,
    const float* __restrict__ g_w2, const float* __restrict__ g_w3,
    const float* __restrict__ g_w4, ushort* __restrict__ Wst)
{
    int tid = threadIdx.x;
    if (blockIdx.x < 96) {
        __shared__ __align__(16) float te[300];
        int v = blockIdx.x;
        for (int k = tid; k < 300; k += 512) te[k] = tanhf(emb[v * 300 + k]);
        __syncthreads();
        int g = tid;
        float acc = b_ih[g];
        const float4* wr = (const float4*)(w_ih + g * 300);
        const float4* tv = (const float4*)te;
        for (int k = 0; k < 75; ++k) {
            float4 w4 = wr[k], t4 = tv[k];
            acc += w4.x * t4.x + w4.y * t4.y + w4.z * t4.z + w4.w * t4.w;
        }
        P[v * 512 + g] = acc;
    } else if (tid < 256) {
        // Wst chunks [li][kc][col][slot], bank-swizzle baked into global layout
        int blk = blockIdx.x - 96;
        int li = blk >> 3, kc = blk & 7, col = tid;
        const float* W = (li == 0) ? g_w2 : (li == 1) ? g_w3 : g_w4;
        ushort* dst = Wst + li * 65536 + kc * 8192;
        for (int kk = 0; kk < 32; ++kk) {
            int slot = (kk >> 3) ^ ((col >> 1) & 3);
            dst[col * 32 + slot * 8 + (kk & 7)] = f2bf(W[(kc * 32 + kk) * 256 + col]);
        }
    }
}

// ---------------- kernel 2: fused LSTM (w_hh LDS-resident bf16) -> Wq -> A1/A2
__global__ __launch_bounds__(256) void kLA(
    const float* __restrict__ P, const float* __restrict__ w_hh,
    const float* __restrict__ b_hh, const float* __restrict__ g_w1,
    const float* __restrict__ g_b1, const int* __restrict__ q_feats,
    const int* __restrict__ q_lens, const float* __restrict__ box_feats,
    ushort* __restrict__ A1, ushort* __restrict__ A2)
{
    __shared__ __align__(16) ushort whh[512 * 128];   // 128 KB, slot-XOR swizzled
    __shared__ __align__(16) float h[128];
    __shared__ __align__(16) float c[128];
    __shared__ float gates[512];
    __shared__ float wq[256];
    __shared__ float box[64][26];
    int b = blockIdx.x, tid = threadIdx.x;          // block 256
    if (tid < 128) { h[tid] = 0.f; c[tid] = 0.f; }
    // stage w_hh -> LDS bf16 with per-row slot XOR (row stride 256B would be 32-way)
    for (int i = tid * 4; i < 65536; i += 1024) {
        int g = i >> 7, k = i & 127, k8 = k >> 3;
        float4 w4 = *(const float4*)&w_hh[i];
        uint2 o;
        o.x = cvtpk(w4.x, w4.y);
        o.y = cvtpk(w4.z, w4.w);
        *(uint2*)&whh[g * 128 + ((k8 ^ (g & 7)) << 3) + (k & 7)] = o;
    }
    for (int idx = tid; idx < 64 * 26; idx += 256) {
        int n = idx / 26, d = idx - n * 26;
        float v;
        if (d < 24)       v = box_feats[(b * 64 + n) * 24 + d];
        else if (d == 24) v = ((n >> 3) - 4) * 0.125f;
        else              v = ((n & 7) - 4) * 0.125f;
        box[n][d] = v;
    }
    __syncthreads();
    int len = q_lens[b];                             // c,h frozen after len
    const int sx = (tid & 7);
    for (int t = 0; t < len; ++t) {
        int idx = q_feats[b * 20 + t];
        #pragma unroll
        for (int gp = 0; gp < 2; ++gp) {
            int g = tid + gp * 256;
            float acc = P[idx * 512 + g] + b_hh[g];
            const ushort* wr = &whh[g * 128];
            #pragma unroll
            for (int k8 = 0; k8 < 16; ++k8) {
                bf16x8 w8 = *(const bf16x8*)&wr[(k8 ^ sx) << 3];
                const float* hv = &h[k8 * 8];
                #pragma unroll
                for (int j = 0; j < 8; ++j)
                    acc += bf2f((ushort)w8[j]) * hv[j];
            }
            gates[g] = acc;
        }
        __syncthreads();
        if (tid < 128) {
            float ig = sigm(gates[tid]);
            float fg = sigm(gates[128 + tid]);
            float gg = tanhf(gates[256 + tid]);
            float og = sigm(gates[384 + tid]);
            float cn = fg * c[tid] + ig * gg;
            c[tid] = cn;
            h[tid] = og * tanhf(cn);
        }
        __syncthreads();
    }
    {
        float acc = g_b1[tid];
        for (int k = 0; k < 128; ++k) acc += c[k] * g_w1[(52 + k) * 256 + tid];
        wq[tid] = acc;
    }
    __syncthreads();
    float w1a[26], w1b[26];
    #pragma unroll
    for (int d = 0; d < 26; ++d) {
        w1a[d] = g_w1[d * 256 + tid];
        w1b[d] = g_w1[(26 + d) * 256 + tid];
    }
    float wqv = wq[tid];
    for (int n = 0; n < 64; ++n) {
        float a1 = 0.f, a2 = wqv;
        #pragma unroll
        for (int d = 0; d < 26; ++d) {
            a1 += box[n][d] * w1a[d];
            a2 += box[n][d] * w1b[d];
        }
        A1[(b * 64 + n) * 256 + tid] = f2bf(a1);
        A2[(b * 64 + n) * 256 + tid] = f2bf(a2);
    }
}

// ---------------- kernel 3: fused pair-MLP; W via global_load_lds DMA dbuf
#define READ_XB(dst, KC)                                                        \
    do {                                                                        \
        _Pragma("unroll")                                                       \
        for (int rt = 0; rt < 8; ++rt) {                                        \
            int row_ = wrow0 + rt * 16 + l15;                                   \
            dst[rt] = *(const bf16x8*)                                          \
                &lds_x[row_ * 256 + (((KC) * 32 + lg * 8) ^ ((row_ & 7) << 3))];\
        }                                                                       \
    } while (0)

#define MFMA_CLUSTER(xuse)                                                      \
    do {                                                                        \
        __builtin_amdgcn_s_setprio(1);                                          \
        _Pragma("unroll")                                                       \
        for (int ct = 0; ct < 4; ++ct) {                                        \
            int col_ = col0 + ct * 16 + l15;                                    \
            bf16x8 wa_ = *(const bf16x8*)                                       \
                &wb[col_ * 32 + ((lg ^ ((col_ >> 1) & 3)) << 3)];               \
            _Pragma("unroll")                                                   \
            for (int rt = 0; rt < 8; ++rt)                                      \
                acc[rt][ct] = __builtin_amdgcn_mfma_f32_16x16x32_bf16(          \
                    wa_, xuse[rt], acc[rt][ct], 0, 0, 0);                       \
        }                                                                       \
        __builtin_amdgcn_s_setprio(0);                                          \
    } while (0)

// issue chunk Q DMA into buf BUF (2 instrs/lane, no registers, no VALU copy)
#define DMA_CHUNK(Q, BUF)                                                       \
    do {                                                                        \
        const char* gs_ = (const char*)Wst + (Q) * 16384 + wv * 1024 + (lane << 4); \
        char* ls_ = ((char*)lds_w[BUF]) + wv * 1024;                            \
        dma16(gs_, ls_);                                                        \
        dma16(gs_ + 8192, ls_ + 8192);                                          \
    } while (0)

#define VM_BAR()                                                                \
    do {                                                                        \
        asm volatile("s_waitcnt vmcnt(0)" ::: "memory");                        \
        __builtin_amdgcn_sched_barrier(0);                                      \
        __builtin_amdgcn_s_barrier();                                           \
    } while (0)

#define CHUNK(kc, xuse, xpre)                                                   \
    do {                                                                        \
        DMA_CHUNK(q + 1, (q + 1) & 1);                                          \
        const ushort* wb = lds_w[q & 1];                                        \
        READ_XB(xpre, (kc) + 1);                                                \
        MFMA_CLUSTER(xuse);                                                     \
        VM_BAR();                                                               \
        ++q;                                                                    \
    } while (0)

__global__ __launch_bounds__(512, 2) void kD(
    const ushort* __restrict__ A1, const ushort* __restrict__ A2,
    const ushort* __restrict__ Wst,
    const float* __restrict__ b2, const float* __restrict__ b3,
    const float* __restrict__ b4, float* __restrict__ partial)
{
    __shared__ __align__(16) ushort lds_x[256 * 256];   // 131072 B, XOR-swizzled rows
    __shared__ __align__(16) ushort lds_w[2][8192];     // 2 x 16384 B (DMA dbuf)

    const int tid = threadIdx.x;
    const int b = blockIdx.x >> 4, iblk = blockIdx.x & 15;   // 4 pairs: i = iblk*4+p
    const int lane = tid & 63, wv = tid >> 6;                // 8 waves
    const int l15 = lane & 15, lg = lane >> 4;
    const int wrow0 = (wv & 1) * 128, col0 = (wv >> 1) * 64; // wave tile 128r x 64c

    // chunk-0 DMA first: lands in buf0 while we build X (a1s aliases buf1)
    DMA_CHUNK(0, 0);

    // ---- stage 4 A1 rows as f32 into buf1 alias (consumed before first buf1 DMA)
    float* a1s = (float*)lds_w[1];    // 4 x 256 floats = 4 KB
    {
        int p = tid >> 8, l = tid & 255;
        a1s[tid]       = bf2f(A1[(b * 64 + iblk * 4 + p)     * 256 + l]);
        a1s[512 + tid] = bf2f(A1[(b * 64 + iblk * 4 + 2 + p) * 256 + l]);
    }
    __syncthreads();

    // ---- build X1 (swizzled): X[p*64+j][l] = relu(a1[p][l] + A2[b,j][l])
    const ushort* A2b = A2 + b * 64 * 256;
    #pragma unroll 4
    for (int p8 = 0; p8 < 16; ++p8) {
        int task = p8 * 512 + tid;
        int row = task >> 5, l0 = (task & 31) << 3;
        int j = row & 63, pr = row >> 6;
        uint4 v = *(const uint4*)(A2b + j * 256 + l0);
        const float* av = a1s + pr * 256 + l0;
        uint vv[4] = {v.x, v.y, v.z, v.w}, ov[4];
        #pragma unroll
        for (int qq = 0; qq < 4; ++qq) {
            float f0 = av[2 * qq]     + bf2f((ushort)(vv[qq] & 0xFFFFu));
            float f1 = av[2 * qq + 1] + bf2f((ushort)(vv[qq] >> 16));
            ov[qq] = cvtpk(fmaxf(f0, 0.f), fmaxf(f1, 0.f));
        }
        *(uint4*)&lds_x[row * 256 + (l0 ^ ((row & 7) << 3))] =
            make_uint4(ov[0], ov[1], ov[2], ov[3]);
    }
    __syncthreads();   // X ready; chunk-0 DMA drained (vmcnt0 inside); buf1 free

    int q = 0;   // linear chunk index li*8+kc
    #pragma unroll 1
    for (int li = 0; li < 3; ++li) {
        const float* bias = (li == 0) ? b2 : (li == 1) ? b3 : b4;
        f32x4 bias4[4];
        #pragma unroll
        for (int ct = 0; ct < 4; ++ct)
            bias4[ct] = *(const f32x4*)(bias + col0 + ct * 16 + lg * 4);
        f32x4 acc[8][4];
        #pragma unroll
        for (int rt = 0; rt < 8; ++rt)
            #pragma unroll
            for (int ct = 0; ct < 4; ++ct)
                acc[rt][ct] = (f32x4){0.f, 0.f, 0.f, 0.f};

        bf16x8 xbA[8], xbB[8];
        READ_XB(xbA, 0);
        CHUNK(0, xbA, xbB);
        CHUNK(1, xbB, xbA);
        CHUNK(2, xbA, xbB);
        CHUNK(3, xbB, xbA);
        CHUNK(4, xbA, xbB);
        CHUNK(5, xbB, xbA);
        CHUNK(6, xbA, xbB);
        // ---- kc = 7 (q = li*8+7, odd -> buf1): MFMA + writeback/reduce
        {
            if (q < 23) DMA_CHUNK(q + 1, 0);   // next layer's chunk 0 -> buf0
            const ushort* wb = lds_w[1];
            MFMA_CLUSTER(xbB);
            ++q;
            if (li < 2) {
                // all lds_x reads for this layer happened by end of kc=6 (barrier'd)
                #pragma unroll
                for (int rt = 0; rt < 8; ++rt) {
                    int row = wrow0 + rt * 16 + l15;
                    int sw = (row & 7) << 3;
                    #pragma unroll
                    for (int ct = 0; ct < 4; ++ct) {
                        f32x4 a = acc[rt][ct];
                        f32x4 bv = bias4[ct];
                        uint2 pk;
                        pk.x = cvtpk(fmaxf(a[0] + bv[0], 0.f), fmaxf(a[1] + bv[1], 0.f));
                        pk.y = cvtpk(fmaxf(a[2] + bv[2], 0.f), fmaxf(a[3] + bv[3], 0.f));
                        *(uint2*)&lds_x[row * 256 + ((col0 + ct * 16 + lg * 4) ^ sw)] = pk;
                    }
                }
                asm volatile("s_waitcnt vmcnt(0) lgkmcnt(0)" ::: "memory");
                __builtin_amdgcn_sched_barrier(0);
                __builtin_amdgcn_s_barrier();
            } else {
                // ---- final layer: reduce 2x64 rows per wave; deterministic
                #pragma unroll
                for (int ct = 0; ct < 4; ++ct) {
                    f32x4 bv = bias4[ct];
                    f32x4 s0 = {0.f, 0.f, 0.f, 0.f}, s1 = {0.f, 0.f, 0.f, 0.f};
                    #pragma unroll
                    for (int rt = 0; rt < 4; ++rt) {
                        f32x4 a = acc[rt][ct];
                        s0[0] += fmaxf(a[0] + bv[0], 0.f); s0[1] += fmaxf(a[1] + bv[1], 0.f);
                        s0[2] += fmaxf(a[2] + bv[2], 0.f); s0[3] += fmaxf(a[3] + bv[3], 0.f);
                    }
                    #pragma unroll
                    for (int rt = 4; rt < 8; ++rt) {
                        f32x4 a = acc[rt][ct];
                        s1[0] += fmaxf(a[0] + bv[0], 0.f); s1[1] += fmaxf(a[1] + bv[1], 0.f);
                        s1[2] += fmaxf(a[2] + bv[2], 0.f); s1[3] += fmaxf(a[3] + bv[3], 0.f);
                    }
                    #pragma unroll
                    for (int m = 1; m < 16; m <<= 1) {
                        #pragma unroll
                        for (int r = 0; r < 4; ++r) {
                            s0[r] += __shfl_xor(s0[r], m, 64);
                            s1[r] += __shfl_xor(s1[r], m, 64);
                        }
                    }
                    if (l15 == 0) {
                        int prow = b * 64 + iblk * 4 + (wv & 1) * 2;
                        float4 o0 = {s0[0], s0[1], s0[2], s0[3]};
                        float4 o1 = {s1[0], s1[1], s1[2], s1[3]};
                        *(float4*)&partial[(prow    ) * 256 + col0 + ct * 16 + lg * 4] = o0;
                        *(float4*)&partial[(prow + 1) * 256 + col0 + ct * 16 + lg * 4] = o1;
                    }
                }
            }
        }
    }
}

// ---------------- kernel 4: fused reduce + f-network, one block per b
__global__ __launch_bounds__(256) void kRF(
    const float* __restrict__ partial,
    const float* __restrict__ f_w1, const float* __restrict__ f_b1,
    const float* __restrict__ f_w2, const float* __restrict__ f_b2,
    const float* __restrict__ f_w3, const float* __restrict__ f_b3,
    float* __restrict__ out)
{
    __shared__ float g[256], y1[256], y2[256];
    int b = blockIdx.x, t = threadIdx.x;       // block 256
    {
        float s = 0.f;
        const float* pb = partial + b * 64 * 256 + t;
        #pragma unroll 8
        for (int i = 0; i < 64; ++i) s += pb[i * 256];
        g[t] = s;
    }
    __syncthreads();
    float acc = f_b1[t];
    for (int k = 0; k < 256; ++k) acc += g[k] * f_w1[k * 256 + t];
    y1[t] = fmaxf(acc, 0.f);
    __syncthreads();
    acc = f_b2[t];
    for (int k = 0; k < 256; ++k) acc += y1[k] * f_w2[k * 256 + t];
    y2[t] = fmaxf(acc, 0.f);
    __syncthreads();
    if (t < 100) {
        float o = f_b3[t];
        for (int k = 0; k < 256; ++k) o += y2[k] * f_w3[k * 100 + t];
        out[b * 100 + t] = o;
    }
}

extern "C" void kernel_launch(void* const* d_in, const int* in_sizes, int n_in,
                              void* d_out, int out_size, void* d_ws, size_t ws_size,
                              hipStream_t stream)
{
    const float* box_feats = (const float*)d_in[0];
    const float* emb   = (const float*)d_in[1];
    const float* w_ih  = (const float*)d_in[2];
    const float* w_hh  = (const float*)d_in[3];
    const float* b_ih  = (const float*)d_in[4];
    const float* b_hh  = (const float*)d_in[5];
    const float* g_w1  = (const float*)d_in[6];
    const float* g_b1  = (const float*)d_in[7];
    const float* g_w2  = (const float*)d_in[8];
    const float* g_b2  = (const float*)d_in[9];
    const float* g_w3  = (const float*)d_in[10];
    const float* g_b3  = (const float*)d_in[11];
    const float* g_w4  = (const float*)d_in[12];
    const float* g_b4  = (const float*)d_in[13];
    const float* f_w1  = (const float*)d_in[14];
    const float* f_b1  = (const float*)d_in[15];
    const float* f_w2  = (const float*)d_in[16];
    const float* f_b2  = (const float*)d_in[17];
    const float* f_w3  = (const float*)d_in[18];
    const float* f_b3  = (const float*)d_in[19];
    const int* q_feats = (const int*)d_in[20];
    const int* q_lens  = (const int*)d_in[21];
    float* out = (float*)d_out;

    char* ws = (char*)d_ws;
    float*  P    = (float*) (ws + 0);          //  96*512*4   = 196608
    ushort* A1   = (ushort*)(ws + 196608);     // 8192*256*2  = 4194304
    ushort* A2   = (ushort*)(ws + 4390912);    // 8192*256*2  = 4194304
    ushort* Wst  = (ushort*)(ws + 8585216);    // 3*65536*2   = 393216
    float*  part = (float*) (ws + 8978432);    // 8192*256*4  = 8388608

    hipLaunchKernelGGL(kPW, dim3(120),  dim3(512), 0, stream,
                       emb, w_ih, b_ih, P, g_w2, g_w3, g_w4, Wst);
    hipLaunchKernelGGL(kLA, dim3(128),  dim3(256), 0, stream,
                       P, w_hh, b_hh, g_w1, g_b1, q_feats, q_lens, box_feats, A1, A2);
    hipLaunchKernelGGL(kD,  dim3(2048), dim3(512), 0, stream,
                       A1, A2, Wst, g_b2, g_b3, g_b4, part);
    hipLaunchKernelGGL(kRF, dim3(128),  dim3(256), 0, stream,
                       part, f_w1, f_b1, f_w2, f_b2, f_w3, f_b3, out);
}

// Round 7
// 362.890 us; speedup vs baseline: 1.4538x; 1.4538x over previous
//
#include <hip/hip_runtime.h>
#include <hip/hip_bf16.h>

typedef unsigned int uint;
typedef unsigned short ushort;
typedef __attribute__((ext_vector_type(8))) short bf16x8;
typedef __attribute__((ext_vector_type(4))) float f32x4;

__device__ __forceinline__ float bf2f(ushort u) {
    return __uint_as_float(((uint)u) << 16);
}
__device__ __forceinline__ ushort f2bf(float f) {
    uint u = __float_as_uint(f);
    u += 0x7FFFu + ((u >> 16) & 1u);   // round-to-nearest-even
    return (ushort)(u >> 16);
}
__device__ __forceinline__ uint cvtpk(float lo, float hi) {
    uint r;
    asm("v_cvt_pk_bf16_f32 %0, %1, %2" : "=v"(r) : "v"(lo), "v"(hi));
    return r;
}
__device__ __forceinline__ float sigm(float x) {
    return 1.0f / (1.0f + expf(-x));
}
// async global->LDS DMA, 16 B per lane; lds dest = wave-uniform base + lane*16
__device__ __forceinline__ void dma16(const void* g, void* l) {
    __builtin_amdgcn_global_load_lds(
        (const __attribute__((address_space(1))) void*)g,
        (__attribute__((address_space(3))) void*)l, 16, 0, 0);
}

// ---------------- kernel 1: fused kP (blocks 0-95) + kW (blocks 96-119)
__global__ __launch_bounds__(512) void kPW(
    const float* __restrict__ emb, const float* __restrict__ w_ih,
    const float* __restrict__ b_ih, float* __restrict__ P,
    const float* __restrict__ g_w2, const float* __restrict__ g_w3,
    const float* __restrict__ g_w4, ushort* __restrict__ Wst)
{
    int tid = threadIdx.x;
    if (blockIdx.x < 96) {
        __shared__ __align__(16) float te[300];
        int v = blockIdx.x;
        for (int k = tid; k < 300; k += 512) te[k] = tanhf(emb[v * 300 + k]);
        __syncthreads();
        int g = tid;
        float acc = b_ih[g];
        const float4* wr = (const float4*)(w_ih + g * 300);
        const float4* tv = (const float4*)te;
        for (int k = 0; k < 75; ++k) {
            float4 w4 = wr[k], t4 = tv[k];
            acc += w4.x * t4.x + w4.y * t4.y + w4.z * t4.z + w4.w * t4.w;
        }
        P[v * 512 + g] = acc;
    } else if (tid < 256) {
        // Wst chunks [li][kc][col][slot], bank-swizzle baked into global layout
        int blk = blockIdx.x - 96;
        int li = blk >> 3, kc = blk & 7, col = tid;
        const float* W = (li == 0) ? g_w2 : (li == 1) ? g_w3 : g_w4;
        ushort* dst = Wst + li * 65536 + kc * 8192;
        for (int kk = 0; kk < 32; ++kk) {
            int slot = (kk >> 3) ^ ((col >> 1) & 3);
            dst[col * 32 + slot * 8 + (kk & 7)] = f2bf(W[(kc * 32 + kk) * 256 + col]);
        }
    }
}

// ---------------- kernel 2: fused LSTM (w_hh LDS-resident bf16) -> Wq -> A1/A2
__global__ __launch_bounds__(256) void kLA(
    const float* __restrict__ P, const float* __restrict__ w_hh,
    const float* __restrict__ b_hh, const float* __restrict__ g_w1,
    const float* __restrict__ g_b1, const int* __restrict__ q_feats,
    const int* __restrict__ q_lens, const float* __restrict__ box_feats,
    ushort* __restrict__ A1, ushort* __restrict__ A2)
{
    __shared__ __align__(16) ushort whh[512 * 128];   // 128 KB, slot-XOR swizzled
    __shared__ __align__(16) float h[128];
    __shared__ __align__(16) float c[128];
    __shared__ float gates[512];
    __shared__ float wq[256];
    __shared__ float box[64][26];
    int b = blockIdx.x, tid = threadIdx.x;          // block 256
    if (tid < 128) { h[tid] = 0.f; c[tid] = 0.f; }
    // stage w_hh -> LDS bf16 with per-row slot XOR (row stride 256B would be 32-way)
    for (int i = tid * 4; i < 65536; i += 1024) {
        int g = i >> 7, k = i & 127, k8 = k >> 3;
        float4 w4 = *(const float4*)&w_hh[i];
        uint2 o;
        o.x = cvtpk(w4.x, w4.y);
        o.y = cvtpk(w4.z, w4.w);
        *(uint2*)&whh[g * 128 + ((k8 ^ (g & 7)) << 3) + (k & 7)] = o;
    }
    for (int idx = tid; idx < 64 * 26; idx += 256) {
        int n = idx / 26, d = idx - n * 26;
        float v;
        if (d < 24)       v = box_feats[(b * 64 + n) * 24 + d];
        else if (d == 24) v = ((n >> 3) - 4) * 0.125f;
        else              v = ((n & 7) - 4) * 0.125f;
        box[n][d] = v;
    }
    __syncthreads();
    int len = q_lens[b];                             // c,h frozen after len
    const int sx = (tid & 7);
    for (int t = 0; t < len; ++t) {
        int idx = q_feats[b * 20 + t];
        #pragma unroll
        for (int gp = 0; gp < 2; ++gp) {
            int g = tid + gp * 256;
            float acc = P[idx * 512 + g] + b_hh[g];
            const ushort* wr = &whh[g * 128];
            #pragma unroll
            for (int k8 = 0; k8 < 16; ++k8) {
                bf16x8 w8 = *(const bf16x8*)&wr[(k8 ^ sx) << 3];
                const float* hv = &h[(k8 ^ sx) * 8];
                #pragma unroll
                for (int j = 0; j < 8; ++j)
                    acc += bf2f((ushort)w8[j]) * hv[j];
            }
            gates[g] = acc;
        }
        __syncthreads();
        if (tid < 128) {
            float ig = sigm(gates[tid]);
            float fg = sigm(gates[128 + tid]);
            float gg = tanhf(gates[256 + tid]);
            float og = sigm(gates[384 + tid]);
            float cn = fg * c[tid] + ig * gg;
            c[tid] = cn;
            h[tid] = og * tanhf(cn);
        }
        __syncthreads();
    }
    {
        float acc = g_b1[tid];
        for (int k = 0; k < 128; ++k) acc += c[k] * g_w1[(52 + k) * 256 + tid];
        wq[tid] = acc;
    }
    __syncthreads();
    float w1a[26], w1b[26];
    #pragma unroll
    for (int d = 0; d < 26; ++d) {
        w1a[d] = g_w1[d * 256 + tid];
        w1b[d] = g_w1[(26 + d) * 256 + tid];
    }
    float wqv = wq[tid];
    for (int n = 0; n < 64; ++n) {
        float a1 = 0.f, a2 = wqv;
        #pragma unroll
        for (int d = 0; d < 26; ++d) {
            a1 += box[n][d] * w1a[d];
            a2 += box[n][d] * w1b[d];
        }
        A1[(b * 64 + n) * 256 + tid] = f2bf(a1);
        A2[(b * 64 + n) * 256 + tid] = f2bf(a2);
    }
}

// ---------------- kernel 3: fused pair-MLP; DMA W dbuf + interleaved xb prefetch
#define MFMA1(wa, xb, a) __builtin_amdgcn_mfma_f32_16x16x32_bf16(wa, xb, a, 0, 0, 0)

#define DMA_CHUNK(Q, BUF)                                                       \
    do {                                                                        \
        const char* gs_ = (const char*)Wst + (Q) * 16384 + wv * 1024 + (lane << 4); \
        char* ls_ = ((char*)lds_w[BUF]) + wv * 1024;                            \
        dma16(gs_, ls_);                                                        \
        dma16(gs_ + 8192, ls_ + 8192);                                          \
    } while (0)

#define READ_XROW(dst, RT, KC)                                                  \
    do {                                                                        \
        int row_ = wrow0 + (RT) * 16 + l15;                                     \
        dst = *(const bf16x8*)&lds_x[row_ * 256                                 \
              + ((((KC) & 7) * 32 + lg * 8) ^ ((row_ & 7) << 3))];              \
    } while (0)

// one K=32 chunk: issue next-chunk DMA, 4 wa reads (1 base + imm offsets),
// rt-outer MFMA with next-chunk xb read interleaved after each row's last use
#define CHUNK(KC, XCUR, XNEXT)                                                  \
    do {                                                                        \
        if (q < 23) DMA_CHUNK(q + 1, (q + 1) & 1);                              \
        const ushort* wb_ = lds_w[q & 1];                                       \
        const ushort* wap_ = &wb_[(col0 + l15) * 32                             \
                                  + ((lg ^ (((col0 + l15) >> 1) & 3)) << 3)];   \
        bf16x8 wa0_ = *(const bf16x8*)(wap_);                                   \
        bf16x8 wa1_ = *(const bf16x8*)(wap_ + 512);                             \
        bf16x8 wa2_ = *(const bf16x8*)(wap_ + 1024);                            \
        bf16x8 wa3_ = *(const bf16x8*)(wap_ + 1536);                            \
        __builtin_amdgcn_s_setprio(1);                                          \
        _Pragma("unroll")                                                       \
        for (int rt_ = 0; rt_ < 8; ++rt_) {                                     \
            acc[rt_][0] = MFMA1(wa0_, XCUR[rt_], acc[rt_][0]);                  \
            acc[rt_][1] = MFMA1(wa1_, XCUR[rt_], acc[rt_][1]);                  \
            acc[rt_][2] = MFMA1(wa2_, XCUR[rt_], acc[rt_][2]);                  \
            acc[rt_][3] = MFMA1(wa3_, XCUR[rt_], acc[rt_][3]);                  \
            READ_XROW(XNEXT[rt_], rt_, (KC) + 1);                               \
        }                                                                       \
        __builtin_amdgcn_s_setprio(0);                                          \
        asm volatile("s_waitcnt vmcnt(0) lgkmcnt(0)" ::: "memory");             \
        __builtin_amdgcn_sched_barrier(0);                                      \
        __builtin_amdgcn_s_barrier();                                           \
        ++q;                                                                    \
    } while (0)

__global__ __launch_bounds__(512, 2) void kD(
    const ushort* __restrict__ A1, const ushort* __restrict__ A2,
    const ushort* __restrict__ Wst,
    const float* __restrict__ b2, const float* __restrict__ b3,
    const float* __restrict__ b4, float* __restrict__ partial)
{
    __shared__ __align__(16) ushort lds_x[256 * 256];   // 131072 B, XOR-swizzled rows
    __shared__ __align__(16) ushort lds_w[2][8192];     // 2 x 16384 B (DMA dbuf)

    const int tid = threadIdx.x;
    const int b = blockIdx.x >> 4, iblk = blockIdx.x & 15;   // 4 pairs: i = iblk*4+p
    const int lane = tid & 63, wv = tid >> 6;                // 8 waves
    const int l15 = lane & 15, lg = lane >> 4;
    const int wrow0 = (wv & 1) * 128, col0 = (wv >> 1) * 64; // wave tile 128r x 64c

    // chunk-0 DMA first: lands in buf0 while we build X (a1s aliases buf1)
    DMA_CHUNK(0, 0);

    // ---- stage 4 A1 rows as f32 into buf1 alias (consumed before buf1's first DMA)
    float* a1s = (float*)lds_w[1];    // 4 x 256 floats = 4 KB
    {
        int p = tid >> 8, l = tid & 255;
        a1s[tid]       = bf2f(A1[(b * 64 + iblk * 4 + p)     * 256 + l]);
        a1s[512 + tid] = bf2f(A1[(b * 64 + iblk * 4 + 2 + p) * 256 + l]);
    }
    __syncthreads();

    // ---- build X1 (swizzled): X[p*64+j][l] = relu(a1[p][l] + A2[b,j][l])
    const ushort* A2b = A2 + b * 64 * 256;
    #pragma unroll 4
    for (int p8 = 0; p8 < 16; ++p8) {
        int task = p8 * 512 + tid;
        int row = task >> 5, l0 = (task & 31) << 3;
        int j = row & 63, pr = row >> 6;
        uint4 v = *(const uint4*)(A2b + j * 256 + l0);
        const float* av = a1s + pr * 256 + l0;
        uint vv[4] = {v.x, v.y, v.z, v.w}, ov[4];
        #pragma unroll
        for (int qq = 0; qq < 4; ++qq) {
            float f0 = av[2 * qq]     + bf2f((ushort)(vv[qq] & 0xFFFFu));
            float f1 = av[2 * qq + 1] + bf2f((ushort)(vv[qq] >> 16));
            ov[qq] = cvtpk(fmaxf(f0, 0.f), fmaxf(f1, 0.f));
        }
        *(uint4*)&lds_x[row * 256 + (l0 ^ ((row & 7) << 3))] =
            make_uint4(ov[0], ov[1], ov[2], ov[3]);
    }
    __syncthreads();   // drains vmcnt too: chunk0 resident in buf0; buf1 free

    int q = 0;   // linear chunk index li*8+kc
    bf16x8 xbA[8], xbB[8];
    #pragma unroll
    for (int rt = 0; rt < 8; ++rt) READ_XROW(xbA[rt], rt, 0);

    #pragma unroll 1
    for (int li = 0; li < 3; ++li) {
        f32x4 acc[8][4];
        #pragma unroll
        for (int rt = 0; rt < 8; ++rt)
            #pragma unroll
            for (int ct = 0; ct < 4; ++ct)
                acc[rt][ct] = (f32x4){0.f, 0.f, 0.f, 0.f};

        CHUNK(0, xbA, xbB);
        CHUNK(1, xbB, xbA);
        CHUNK(2, xbA, xbB);
        CHUNK(3, xbB, xbA);
        CHUNK(4, xbA, xbB);
        CHUNK(5, xbB, xbA);
        CHUNK(6, xbA, xbB);
        CHUNK(7, xbB, xbA);   // its XNEXT read (slice 0) is pre-writeback, unused

        const float* bias = (li == 0) ? b2 : (li == 1) ? b3 : b4;
        f32x4 bv0 = *(const f32x4*)(bias + col0 + lg * 4);
        f32x4 bv1 = *(const f32x4*)(bias + col0 + 16 + lg * 4);
        f32x4 bv2 = *(const f32x4*)(bias + col0 + 32 + lg * 4);
        f32x4 bv3 = *(const f32x4*)(bias + col0 + 48 + lg * 4);

        if (li < 2) {
            // all lds_x reads done (pre-barrier in CHUNK(7)); overwrite in place
            #pragma unroll
            for (int rt = 0; rt < 8; ++rt) {
                int row = wrow0 + rt * 16 + l15;
                int sw = (row & 7) << 3;
                #pragma unroll
                for (int ct = 0; ct < 4; ++ct) {
                    f32x4 a = acc[rt][ct];
                    f32x4 bv = (ct == 0) ? bv0 : (ct == 1) ? bv1 : (ct == 2) ? bv2 : bv3;
                    uint2 pk;
                    pk.x = cvtpk(fmaxf(a[0] + bv[0], 0.f), fmaxf(a[1] + bv[1], 0.f));
                    pk.y = cvtpk(fmaxf(a[2] + bv[2], 0.f), fmaxf(a[3] + bv[3], 0.f));
                    *(uint2*)&lds_x[row * 256 + ((col0 + ct * 16 + lg * 4) ^ sw)] = pk;
                }
            }
            asm volatile("s_waitcnt lgkmcnt(0)" ::: "memory");
            __builtin_amdgcn_sched_barrier(0);
            __builtin_amdgcn_s_barrier();
            #pragma unroll
            for (int rt = 0; rt < 8; ++rt) READ_XROW(xbA[rt], rt, 0);
        } else {
            // ---- final layer: reduce 2x64 rows per wave; deterministic
            #pragma unroll
            for (int ct = 0; ct < 4; ++ct) {
                f32x4 bv = (ct == 0) ? bv0 : (ct == 1) ? bv1 : (ct == 2) ? bv2 : bv3;
                f32x4 s0 = {0.f, 0.f, 0.f, 0.f}, s1 = {0.f, 0.f, 0.f, 0.f};
                #pragma unroll
                for (int rt = 0; rt < 4; ++rt) {
                    f32x4 a = acc[rt][ct];
                    s0[0] += fmaxf(a[0] + bv[0], 0.f); s0[1] += fmaxf(a[1] + bv[1], 0.f);
                    s0[2] += fmaxf(a[2] + bv[2], 0.f); s0[3] += fmaxf(a[3] + bv[3], 0.f);
                }
                #pragma unroll
                for (int rt = 4; rt < 8; ++rt) {
                    f32x4 a = acc[rt][ct];
                    s1[0] += fmaxf(a[0] + bv[0], 0.f); s1[1] += fmaxf(a[1] + bv[1], 0.f);
                    s1[2] += fmaxf(a[2] + bv[2], 0.f); s1[3] += fmaxf(a[3] + bv[3], 0.f);
                }
                #pragma unroll
                for (int m = 1; m < 16; m <<= 1) {
                    #pragma unroll
                    for (int r = 0; r < 4; ++r) {
                        s0[r] += __shfl_xor(s0[r], m, 64);
                        s1[r] += __shfl_xor(s1[r], m, 64);
                    }
                }
                if (l15 == 0) {
                    int prow = b * 64 + iblk * 4 + (wv & 1) * 2;
                    float4 o0 = {s0[0], s0[1], s0[2], s0[3]};
                    float4 o1 = {s1[0], s1[1], s1[2], s1[3]};
                    *(float4*)&partial[(prow    ) * 256 + col0 + ct * 16 + lg * 4] = o0;
                    *(float4*)&partial[(prow + 1) * 256 + col0 + ct * 16 + lg * 4] = o1;
                }
            }
        }
    }
}

// ---------------- kernel 4: fused reduce + f-network, one block per b
__global__ __launch_bounds__(256) void kRF(
    const float* __restrict__ partial,
    const float* __restrict__ f_w1, const float* __restrict__ f_b1,
    const float* __restrict__ f_w2, const float* __restrict__ f_b2,
    const float* __restrict__ f_w3, const float* __restrict__ f_b3,
    float* __restrict__ out)
{
    __shared__ float g[256], y1[256], y2[256];
    int b = blockIdx.x, t = threadIdx.x;       // block 256
    {
        float s = 0.f;
        const float* pb = partial + b * 64 * 256 + t;
        #pragma unroll 8
        for (int i = 0; i < 64; ++i) s += pb[i * 256];
        g[t] = s;
    }
    __syncthreads();
    float acc = f_b1[t];
    for (int k = 0; k < 256; ++k) acc += g[k] * f_w1[k * 256 + t];
    y1[t] = fmaxf(acc, 0.f);
    __syncthreads();
    acc = f_b2[t];
    for (int k = 0; k < 256; ++k) acc += y1[k] * f_w2[k * 256 + t];
    y2[t] = fmaxf(acc, 0.f);
    __syncthreads();
    if (t < 100) {
        float o = f_b3[t];
        for (int k = 0; k < 256; ++k) o += y2[k] * f_w3[k * 100 + t];
        out[b * 100 + t] = o;
    }
}

extern "C" void kernel_launch(void* const* d_in, const int* in_sizes, int n_in,
                              void* d_out, int out_size, void* d_ws, size_t ws_size,
                              hipStream_t stream)
{
    const float* box_feats = (const float*)d_in[0];
    const float* emb   = (const float*)d_in[1];
    const float* w_ih  = (const float*)d_in[2];
    const float* w_hh  = (const float*)d_in[3];
    const float* b_ih  = (const float*)d_in[4];
    const float* b_hh  = (const float*)d_in[5];
    const float* g_w1  = (const float*)d_in[6];
    const float* g_b1  = (const float*)d_in[7];
    const float* g_w2  = (const float*)d_in[8];
    const float* g_b2  = (const float*)d_in[9];
    const float* g_w3  = (const float*)d_in[10];
    const float* g_b3  = (const float*)d_in[11];
    const float* g_w4  = (const float*)d_in[12];
    const float* g_b4  = (const float*)d_in[13];
    const float* f_w1  = (const float*)d_in[14];
    const float* f_b1  = (const float*)d_in[15];
    const float* f_w2  = (const float*)d_in[16];
    const float* f_b2  = (const float*)d_in[17];
    const float* f_w3  = (const float*)d_in[18];
    const float* f_b3  = (const float*)d_in[19];
    const int* q_feats = (const int*)d_in[20];
    const int* q_lens  = (const int*)d_in[21];
    float* out = (float*)d_out;

    char* ws = (char*)d_ws;
    float*  P    = (float*) (ws + 0);          //  96*512*4   = 196608
    ushort* A1   = (ushort*)(ws + 196608);     // 8192*256*2  = 4194304
    ushort* A2   = (ushort*)(ws + 4390912);    // 8192*256*2  = 4194304
    ushort* Wst  = (ushort*)(ws + 8585216);    // 3*65536*2   = 393216
    float*  part = (float*) (ws + 8978432);    // 8192*256*4  = 8388608

    hipLaunchKernelGGL(kPW, dim3(120),  dim3(512), 0, stream,
                       emb, w_ih, b_ih, P, g_w2, g_w3, g_w4, Wst);
    hipLaunchKernelGGL(kLA, dim3(128),  dim3(256), 0, stream,
                       P, w_hh, b_hh, g_w1, g_b1, q_feats, q_lens, box_feats, A1, A2);
    hipLaunchKernelGGL(kD,  dim3(2048), dim3(512), 0, stream,
                       A1, A2, Wst, g_b2, g_b3, g_b4, part);
    hipLaunchKernelGGL(kRF, dim3(128),  dim3(256), 0, stream,
                       part, f_w1, f_b1, f_w2, f_b2, f_w3, f_b3, out);
}